// Round 1
// baseline (4067.230 us; speedup 1.0000x reference)
//
#include <hip/hip_runtime.h>
#include <hip/hip_bf16.h>
#include <math.h>

// Problem constants (ReprogrammingLayer)
#define B_SZ 8
#define L_SZ 1024
#define S_SZ 1000
#define DM   1024      // d_model = H*E
#define DL   4096      // d_llm
#define NH   16
#define EH   64

// ---------------------------------------------------------------------------
// Generic tiled GEMM with bias: C[M,N] = A[M,K] @ B[K,N] + bias[N]
// 64x64 tile, BK=16, 256 threads (16x16), 4x4 accum per thread.
// LDS rows padded to 68 floats: float4-aligned (272 B = 17*16) and
// conflict-light for the b128 inner reads.
// ---------------------------------------------------------------------------
__global__ __launch_bounds__(256) void gemm_bias_kernel(
    const float* __restrict__ A, const float* __restrict__ Bm,
    const float* __restrict__ bias, float* __restrict__ C,
    int M, int N, int K)
{
    __shared__ __align__(16) float As[16][68];   // As[k][m]
    __shared__ __align__(16) float Bs[16][68];   // Bs[k][n]

    const int tid = threadIdx.x;
    const int tx = tid & 15;        // output col group
    const int ty = tid >> 4;        // output row group
    const int m0 = blockIdx.y * 64;
    const int n0 = blockIdx.x * 64;

    float acc[4][4] = {};

    for (int k0 = 0; k0 < K; k0 += 16) {
        // A tile: 64 rows x 16 k  (consecutive threads -> consecutive k)
        for (int i = tid; i < 1024; i += 256) {
            int r  = i >> 4;
            int kk = i & 15;
            int gm = m0 + r;
            As[kk][r] = (gm < M) ? A[(size_t)gm * K + (k0 + kk)] : 0.f;
        }
        // B tile: 16 k x 64 n  (consecutive threads -> consecutive n, coalesced)
        for (int i = tid; i < 1024; i += 256) {
            int kk = i >> 6;
            int c  = i & 63;
            Bs[kk][c] = Bm[(size_t)(k0 + kk) * N + (n0 + c)];
        }
        __syncthreads();

#pragma unroll
        for (int kk = 0; kk < 16; ++kk) {
            float4 a4 = *(const float4*)&As[kk][ty * 4];
            float4 b4 = *(const float4*)&Bs[kk][tx * 4];
            float a[4] = {a4.x, a4.y, a4.z, a4.w};
            float b[4] = {b4.x, b4.y, b4.z, b4.w};
#pragma unroll
            for (int i = 0; i < 4; ++i)
#pragma unroll
                for (int j = 0; j < 4; ++j)
                    acc[i][j] += a[i] * b[j];
        }
        __syncthreads();
    }

#pragma unroll
    for (int i = 0; i < 4; ++i) {
        int gm = m0 + ty * 4 + i;
        if (gm < M) {
            float4 o4;
            o4.x = acc[i][0] + bias[n0 + tx * 4 + 0];
            o4.y = acc[i][1] + bias[n0 + tx * 4 + 1];
            o4.z = acc[i][2] + bias[n0 + tx * 4 + 2];
            o4.w = acc[i][3] + bias[n0 + tx * 4 + 3];
            *(float4*)&C[(size_t)gm * N + n0 + tx * 4] = o4;
        }
    }
}

// ---------------------------------------------------------------------------
// Flash-style attention, one block = 64 Q rows of one (b,h).
// q,k,v: row-major (rows, H*E); o: same layout as q.
// Online softmax over S in chunks of 64. K^T and P share one LDS buffer
// (total LDS ~49 KB -> 3 blocks/CU).
// Pad = 65 floats: scalar LDS reads land on 2-way-max bank aliasing (free).
// ---------------------------------------------------------------------------
__global__ __launch_bounds__(256) void attn_kernel(
    const float* __restrict__ q, const float* __restrict__ k,
    const float* __restrict__ v, float* __restrict__ o)
{
    __shared__ float qs[64][65];    // qs[r][e]
    __shared__ float kp[64][65];    // phase 1: kt[e][s]; phase 2: ps[r][s]
    __shared__ float vs[64][65];    // vs[s][e]

    const int tid = threadIdx.x;
    const int tx = tid & 15;
    const int ty = tid >> 4;
    const int bh = blockIdx.y;
    const int b  = bh >> 4;
    const int h  = bh & 15;
    const int l0 = blockIdx.x * 64;
    const size_t qbase = ((size_t)(b * L_SZ + l0)) * DM + (size_t)h * EH;

    // load Q tile (stays resident the whole kernel)
    for (int i = tid; i < 4096; i += 256) {
        int r = i >> 6, e = i & 63;
        qs[r][e] = q[qbase + (size_t)r * DM + e];
    }

    float m_r[4], l_r[4], acc[4][4];
#pragma unroll
    for (int i = 0; i < 4; ++i) {
        m_r[i] = -1e30f;
        l_r[i] = 0.f;
#pragma unroll
        for (int j = 0; j < 4; ++j) acc[i][j] = 0.f;
    }
    __syncthreads();

    for (int s0 = 0; s0 < S_SZ; s0 += 64) {
        // load K chunk transposed + V chunk (guard S tail, fill 0)
        for (int i = tid; i < 4096; i += 256) {
            int s = i >> 6, e = i & 63;
            int sg = s0 + s;
            float kv = (sg < S_SZ) ? k[(size_t)sg * DM + h * EH + e] : 0.f;
            float vv = (sg < S_SZ) ? v[(size_t)sg * DM + h * EH + e] : 0.f;
            kp[e][s] = kv;
            vs[s][e] = vv;
        }
        __syncthreads();

        // scores: sc[i][j] = q[row ty*4+i] . k[col s0+tx*4+j]
        float sc[4][4] = {};
#pragma unroll
        for (int e = 0; e < 64; ++e) {
            float qv[4], kv[4];
#pragma unroll
            for (int i = 0; i < 4; ++i) qv[i] = qs[ty * 4 + i][e];
#pragma unroll
            for (int j = 0; j < 4; ++j) kv[j] = kp[e][tx * 4 + j];
#pragma unroll
            for (int i = 0; i < 4; ++i)
#pragma unroll
                for (int j = 0; j < 4; ++j)
                    sc[i][j] += qv[i] * kv[j];
        }
#pragma unroll
        for (int i = 0; i < 4; ++i)
#pragma unroll
            for (int j = 0; j < 4; ++j) {
                sc[i][j] *= 0.125f;   // 1/sqrt(64)
                if (s0 + tx * 4 + j >= S_SZ) sc[i][j] = -1e30f;
            }

        // online softmax: row max across the 16 tx lanes (same 16-lane group)
        float cm[4];
#pragma unroll
        for (int i = 0; i < 4; ++i)
            cm[i] = fmaxf(fmaxf(sc[i][0], sc[i][1]), fmaxf(sc[i][2], sc[i][3]));
#pragma unroll
        for (int off = 1; off < 16; off <<= 1)
#pragma unroll
            for (int i = 0; i < 4; ++i)
                cm[i] = fmaxf(cm[i], __shfl_xor(cm[i], off));

        float m_new[4], alpha[4], p[4][4], rs[4];
#pragma unroll
        for (int i = 0; i < 4; ++i) {
            m_new[i] = fmaxf(m_r[i], cm[i]);
            alpha[i] = __expf(m_r[i] - m_new[i]);
            rs[i] = 0.f;
#pragma unroll
            for (int j = 0; j < 4; ++j) {
                p[i][j] = __expf(sc[i][j] - m_new[i]);
                rs[i] += p[i][j];
            }
        }
#pragma unroll
        for (int off = 1; off < 16; off <<= 1)
#pragma unroll
            for (int i = 0; i < 4; ++i)
                rs[i] += __shfl_xor(rs[i], off);
#pragma unroll
        for (int i = 0; i < 4; ++i) {
            l_r[i] = l_r[i] * alpha[i] + rs[i];
            m_r[i] = m_new[i];
#pragma unroll
            for (int j = 0; j < 4; ++j) acc[i][j] *= alpha[i];
        }

        // P -> LDS (reuse kp buffer; must wait until all K^T reads are done)
        __syncthreads();
#pragma unroll
        for (int i = 0; i < 4; ++i)
#pragma unroll
            for (int j = 0; j < 4; ++j)
                kp[ty * 4 + i][tx * 4 + j] = p[i][j];
        __syncthreads();

        // PV: acc[i][j] += sum_s ps[r][s] * vs[s][e]
        for (int s = 0; s < 64; ++s) {
            float pv[4], vv[4];
#pragma unroll
            for (int i = 0; i < 4; ++i) pv[i] = kp[ty * 4 + i][s];
#pragma unroll
            for (int j = 0; j < 4; ++j) vv[j] = vs[s][tx * 4 + j];
#pragma unroll
            for (int i = 0; i < 4; ++i)
#pragma unroll
                for (int j = 0; j < 4; ++j)
                    acc[i][j] += pv[i] * vv[j];
        }
        __syncthreads();   // before next chunk overwrites kp/vs
    }

    // epilogue: normalize and store
#pragma unroll
    for (int i = 0; i < 4; ++i) {
        float inv_l = 1.f / l_r[i];
        float4 o4;
        o4.x = acc[i][0] * inv_l;
        o4.y = acc[i][1] * inv_l;
        o4.z = acc[i][2] * inv_l;
        o4.w = acc[i][3] * inv_l;
        *(float4*)&o[qbase + (size_t)(ty * 4 + i) * DM + tx * 4] = o4;
    }
}

// ---------------------------------------------------------------------------
extern "C" void kernel_launch(void* const* d_in, const int* in_sizes, int n_in,
                              void* d_out, int out_size, void* d_ws, size_t ws_size,
                              hipStream_t stream)
{
    const float* target = (const float*)d_in[0];   // (B,L,DM)
    const float* source = (const float*)d_in[1];   // (S,DL)
    const float* value  = (const float*)d_in[2];   // (S,DL)
    const float* Wq = (const float*)d_in[3];       // (DM, DM)
    const float* bq = (const float*)d_in[4];
    const float* Wk = (const float*)d_in[5];       // (DL, DM)
    const float* bk = (const float*)d_in[6];
    const float* Wv = (const float*)d_in[7];       // (DL, DM)
    const float* bv = (const float*)d_in[8];
    const float* Wo = (const float*)d_in[9];       // (DM, DL)
    const float* bo = (const float*)d_in[10];
    float* out = (float*)d_out;                    // (B,L,DL)

    // workspace layout (fp32): q | k | v | attn_out  = ~75.3 MB
    float* qbuf = (float*)d_ws;                          // 8192*1024
    float* kbuf = qbuf + (size_t)B_SZ * L_SZ * DM;       // 1000*1024
    float* vbuf = kbuf + (size_t)S_SZ * DM;              // 1000*1024
    float* attn = vbuf + (size_t)S_SZ * DM;              // 8192*1024

    const dim3 blk(256);
    const int ML = B_SZ * L_SZ;   // 8192

    // Q = target @ Wq + bq        (8192 x 1024) @ (1024 x 1024)
    gemm_bias_kernel<<<dim3(DM / 64, ML / 64), blk, 0, stream>>>(
        target, Wq, bq, qbuf, ML, DM, DM);
    // K = source @ Wk + bk        (1000 x 4096) @ (4096 x 1024)
    gemm_bias_kernel<<<dim3(DM / 64, (S_SZ + 63) / 64), blk, 0, stream>>>(
        source, Wk, bk, kbuf, S_SZ, DM, DL);
    // V = value @ Wv + bv
    gemm_bias_kernel<<<dim3(DM / 64, (S_SZ + 63) / 64), blk, 0, stream>>>(
        value, Wv, bv, vbuf, S_SZ, DM, DL);
    // attention
    attn_kernel<<<dim3(L_SZ / 64, B_SZ * NH), blk, 0, stream>>>(
        qbuf, kbuf, vbuf, attn);
    // out = attn @ Wo + bo        (8192 x 1024) @ (1024 x 4096)
    gemm_bias_kernel<<<dim3(DL / 64, ML / 64), blk, 0, stream>>>(
        attn, Wo, bo, out, ML, DL, DM);
}

// Round 2
// 1756.594 us; speedup vs baseline: 2.3154x; 2.3154x over previous
//
#include <hip/hip_runtime.h>
#include <hip/hip_bf16.h>
#include <math.h>

#define B_SZ 8
#define L_SZ 1024
#define S_SZ 1000
#define DM   1024      // d_model = H*E = q/k/v row stride
#define DL   4096      // d_llm
#define NH   16
#define EH   64

typedef __bf16 bf16x8 __attribute__((ext_vector_type(8)));
typedef __bf16 bf16x4 __attribute__((ext_vector_type(4)));
typedef float  f32x4  __attribute__((ext_vector_type(4)));

// async 16-byte global -> LDS (DMA, no VGPR round trip)
__device__ __forceinline__ void async16(const void* g, void* l) {
    __builtin_amdgcn_global_load_lds(
        (const __attribute__((address_space(1))) void*)g,
        (__attribute__((address_space(3))) void*)l, 16, 0, 0);
}

// ---------------------------------------------------------------------------
// cast fp32 -> bf16, 4 elems/thread
// ---------------------------------------------------------------------------
__global__ __launch_bounds__(256) void cast_f2b_kernel(
    const float* __restrict__ in, __bf16* __restrict__ out, int n4)
{
    int i = blockIdx.x * 256 + threadIdx.x;
    if (i < n4) {
        float4 x = ((const float4*)in)[i];
        bf16x4 y;
        y.x = (__bf16)x.x; y.y = (__bf16)x.y;
        y.z = (__bf16)x.z; y.w = (__bf16)x.w;
        ((bf16x4*)out)[i] = y;
    }
}

// ---------------------------------------------------------------------------
// W (K,N) fp32 -> WT (N,K) bf16. 64x64 tile. K,N multiples of 64.
// ---------------------------------------------------------------------------
__global__ __launch_bounds__(256) void transpose_cast_kernel(
    const float* __restrict__ W, __bf16* __restrict__ WT, int K, int N)
{
    __shared__ float t[64][68];
    const int k0 = blockIdx.y * 64, n0 = blockIdx.x * 64;
    const int tx = threadIdx.x & 15, ty = threadIdx.x >> 4;

#pragma unroll
    for (int tt = 0; tt < 4; ++tt) {
        int r = ty + 16 * tt;
        float4 x = *(const float4*)&W[(size_t)(k0 + r) * N + n0 + 4 * tx];
        *(float4*)&t[r][4 * tx] = x;
    }
    __syncthreads();
#pragma unroll
    for (int tt = 0; tt < 4; ++tt) {
        int n = ty + 16 * tt;
        bf16x4 y;
        y.x = (__bf16)t[4 * tx + 0][n];
        y.y = (__bf16)t[4 * tx + 1][n];
        y.z = (__bf16)t[4 * tx + 2][n];
        y.w = (__bf16)t[4 * tx + 3][n];
        *(bf16x4*)&WT[(size_t)(n0 + n) * K + k0 + 4 * tx] = y;
    }
}

// ---------------------------------------------------------------------------
// m97-style bf16 MFMA GEMM: C[M,N] = A[M,K] @ BT[N,K]^T + bias
// 128x128 tile, BK=32, 256 thr = 4 waves (2x2), 4x4 MFMA tiles/wave.
// global_load_lds width 16. N, K multiples of 128/32; M-tail clamped.
// ---------------------------------------------------------------------------
template <bool OUT_BF16>
__global__ __launch_bounds__(256) void gemm_bt_kernel(
    const __bf16* __restrict__ A, const __bf16* __restrict__ BT,
    const float* __restrict__ bias, void* __restrict__ Cv,
    int M, int N, int K)
{
    __shared__ __bf16 As[128 * 32];   // row-major, 64 B/row
    __shared__ __bf16 Bs[128 * 32];

    const int tid  = threadIdx.x;
    const int lane = tid & 63;
    const int wave = tid >> 6;
    const int wr   = wave >> 1;
    const int wc   = wave & 1;
    const int m0   = blockIdx.y * 128;
    const int n0   = blockIdx.x * 128;
    const int lm   = lane & 15;        // fragment row/col within 16
    const int lq   = lane >> 4;        // k-quad

    f32x4 acc[4][4];
#pragma unroll
    for (int i = 0; i < 4; ++i)
#pragma unroll
        for (int j = 0; j < 4; ++j)
            acc[i][j] = (f32x4){0.f, 0.f, 0.f, 0.f};

    for (int k0 = 0; k0 < K; k0 += 32) {
#pragma unroll
        for (int t = 0; t < 2; ++t) {
            int chunk = t * 256 + tid;          // 0..511, 16 B each
            int r     = chunk >> 2;             // tile row 0..127
            int koff  = (chunk & 3) * 8;
            int gm = m0 + r; if (gm >= M) gm = M - 1;
            async16(A  + (size_t)gm * K + k0 + koff, (char*)As + chunk * 16);
            int gn = n0 + r;                    // N multiple of 128
            async16(BT + (size_t)gn * K + k0 + koff, (char*)Bs + chunk * 16);
        }
        __syncthreads();

        bf16x8 af[4], bf_[4];
#pragma unroll
        for (int i = 0; i < 4; ++i) {
            af[i]  = *(const bf16x8*)&As[(wr * 64 + i * 16 + lm) * 32 + lq * 8];
            bf_[i] = *(const bf16x8*)&Bs[(wc * 64 + i * 16 + lm) * 32 + lq * 8];
        }
#pragma unroll
        for (int i = 0; i < 4; ++i)
#pragma unroll
            for (int j = 0; j < 4; ++j)
                acc[i][j] = __builtin_amdgcn_mfma_f32_16x16x32_bf16(
                    af[i], bf_[j], acc[i][j], 0, 0, 0);
        __syncthreads();
    }

    // C/D layout: col = lane&15, row = (lane>>4)*4 + reg
#pragma unroll
    for (int i = 0; i < 4; ++i) {
        int gm0 = m0 + wr * 64 + i * 16 + lq * 4;
#pragma unroll
        for (int j = 0; j < 4; ++j) {
            int gn = n0 + wc * 64 + j * 16 + lm;
            float bv = bias[gn];
#pragma unroll
            for (int r = 0; r < 4; ++r) {
                int gm = gm0 + r;
                if (gm < M) {
                    float val = acc[i][j][r] + bv;
                    if (OUT_BF16)
                        ((__bf16*)Cv)[(size_t)gm * N + gn] = (__bf16)val;
                    else
                        ((float*)Cv)[(size_t)gm * N + gn] = val;
                }
            }
        }
    }
}

// ---------------------------------------------------------------------------
// Flash attention, fp32 compute, bf16 in/out. Block = 64 Q rows x one (b,h).
// Strided output mapping (cols tx+16j, rows ty+16i) -> LDS reads are
// broadcast or 2-way (free). float4 dots; V transposed in LDS for PV.
// LDS = 3 * 64*68*4 = 52 KB -> 3 blocks/CU.
// ---------------------------------------------------------------------------
__global__ __launch_bounds__(256) void attn_kernel(
    const __bf16* __restrict__ q, const __bf16* __restrict__ k,
    const __bf16* __restrict__ v, __bf16* __restrict__ o)
{
    __shared__ float qs[64][68];   // [r][e]
    __shared__ float kp[64][68];   // phase1: K-chunk [s][e]; phase2: P [r][s]
    __shared__ float vt[64][68];   // V^T [e][s]

    const int tid = threadIdx.x;
    const int tx = tid & 15;
    const int ty = tid >> 4;
    const int bh = blockIdx.y;
    const int b  = bh >> 4;
    const int h  = bh & 15;
    const int l0 = blockIdx.x * 64;
    const size_t qbase = ((size_t)(b * L_SZ + l0)) * DM + (size_t)h * EH;

    // Q tile (resident all kernel)
#pragma unroll
    for (int t = 0; t < 4; ++t) {
        int idx = t * 256 + tid;
        int r = idx >> 4, e0 = (idx & 15) * 4;
        bf16x4 x = *(const bf16x4*)&q[qbase + (size_t)r * DM + e0];
        qs[r][e0 + 0] = (float)x.x; qs[r][e0 + 1] = (float)x.y;
        qs[r][e0 + 2] = (float)x.z; qs[r][e0 + 3] = (float)x.w;
    }

    float m_r[4], l_r[4], acc[4][4];
#pragma unroll
    for (int i = 0; i < 4; ++i) {
        m_r[i] = -1e30f; l_r[i] = 0.f;
#pragma unroll
        for (int j = 0; j < 4; ++j) acc[i][j] = 0.f;
    }

    for (int s0 = 0; s0 < S_SZ; s0 += 64) {
        __syncthreads();   // prev chunk's PV reads done (and Q-load, iter 0)
        // stage K chunk [s][e] and V^T [e][s]
#pragma unroll
        for (int t = 0; t < 4; ++t) {
            int idx = t * 256 + tid;
            int r = idx >> 4, e0 = (idx & 15) * 4;
            int sg = s0 + r; if (sg >= S_SZ) sg = S_SZ - 1;
            size_t base = (size_t)sg * DM + (size_t)h * EH + e0;
            bf16x4 kx = *(const bf16x4*)&k[base];
            kp[r][e0 + 0] = (float)kx.x; kp[r][e0 + 1] = (float)kx.y;
            kp[r][e0 + 2] = (float)kx.z; kp[r][e0 + 3] = (float)kx.w;
            bf16x4 vx = *(const bf16x4*)&v[base];
            vt[e0 + 0][r] = (float)vx.x; vt[e0 + 1][r] = (float)vx.y;
            vt[e0 + 2][r] = (float)vx.z; vt[e0 + 3][r] = (float)vx.w;
        }
        __syncthreads();

        // QK^T: sc[i][j] = q[ty+16i] . k[tx+16j]
        float sc[4][4] = {};
#pragma unroll
        for (int e0 = 0; e0 < 64; e0 += 4) {
            float4 qv[4], kv[4];
#pragma unroll
            for (int i = 0; i < 4; ++i) qv[i] = *(const float4*)&qs[ty + 16 * i][e0];
#pragma unroll
            for (int j = 0; j < 4; ++j) kv[j] = *(const float4*)&kp[tx + 16 * j][e0];
#pragma unroll
            for (int i = 0; i < 4; ++i)
#pragma unroll
                for (int j = 0; j < 4; ++j)
                    sc[i][j] += qv[i].x * kv[j].x + qv[i].y * kv[j].y
                              + qv[i].z * kv[j].z + qv[i].w * kv[j].w;
        }
#pragma unroll
        for (int i = 0; i < 4; ++i)
#pragma unroll
            for (int j = 0; j < 4; ++j) {
                sc[i][j] *= 0.125f;
                if (s0 + tx + 16 * j >= S_SZ) sc[i][j] = -1e30f;
            }

        // online softmax (row-reduce across the 16 tx lanes)
        float cm[4];
#pragma unroll
        for (int i = 0; i < 4; ++i)
            cm[i] = fmaxf(fmaxf(sc[i][0], sc[i][1]), fmaxf(sc[i][2], sc[i][3]));
#pragma unroll
        for (int off = 1; off < 16; off <<= 1)
#pragma unroll
            for (int i = 0; i < 4; ++i)
                cm[i] = fmaxf(cm[i], __shfl_xor(cm[i], off));

        float p[4][4], rs[4], alpha[4];
#pragma unroll
        for (int i = 0; i < 4; ++i) {
            float m_new = fmaxf(m_r[i], cm[i]);
            alpha[i] = __expf(m_r[i] - m_new);
            m_r[i] = m_new;
            rs[i] = 0.f;
#pragma unroll
            for (int j = 0; j < 4; ++j) {
                p[i][j] = __expf(sc[i][j] - m_new);
                rs[i] += p[i][j];
            }
        }
#pragma unroll
        for (int off = 1; off < 16; off <<= 1)
#pragma unroll
            for (int i = 0; i < 4; ++i)
                rs[i] += __shfl_xor(rs[i], off);
#pragma unroll
        for (int i = 0; i < 4; ++i) {
            l_r[i] = l_r[i] * alpha[i] + rs[i];
#pragma unroll
            for (int j = 0; j < 4; ++j) acc[i][j] *= alpha[i];
        }

        // P -> kp (all QK reads of kp are done; need barrier first)
        __syncthreads();
#pragma unroll
        for (int i = 0; i < 4; ++i)
#pragma unroll
            for (int j = 0; j < 4; ++j)
                kp[ty + 16 * i][tx + 16 * j] = p[i][j];
        __syncthreads();

        // PV: acc[i][j] += P[ty+16i] . V^T[tx+16j]  (dot over s)
#pragma unroll
        for (int s = 0; s < 64; s += 4) {
            float4 pv[4], vv[4];
#pragma unroll
            for (int i = 0; i < 4; ++i) pv[i] = *(const float4*)&kp[ty + 16 * i][s];
#pragma unroll
            for (int j = 0; j < 4; ++j) vv[j] = *(const float4*)&vt[tx + 16 * j][s];
#pragma unroll
            for (int i = 0; i < 4; ++i)
#pragma unroll
                for (int j = 0; j < 4; ++j)
                    acc[i][j] += pv[i].x * vv[j].x + pv[i].y * vv[j].y
                               + pv[i].z * vv[j].z + pv[i].w * vv[j].w;
        }
    }

    // epilogue: normalize, store bf16
#pragma unroll
    for (int i = 0; i < 4; ++i) {
        float inv_l = 1.f / l_r[i];
#pragma unroll
        for (int j = 0; j < 4; ++j)
            o[qbase + (size_t)(ty + 16 * i) * DM + tx + 16 * j] =
                (__bf16)(acc[i][j] * inv_l);
    }
}

// ---------------------------------------------------------------------------
extern "C" void kernel_launch(void* const* d_in, const int* in_sizes, int n_in,
                              void* d_out, int out_size, void* d_ws, size_t ws_size,
                              hipStream_t stream)
{
    const float* target = (const float*)d_in[0];
    const float* source = (const float*)d_in[1];
    const float* value  = (const float*)d_in[2];
    const float* Wq = (const float*)d_in[3];
    const float* bq = (const float*)d_in[4];
    const float* Wk = (const float*)d_in[5];
    const float* bk = (const float*)d_in[6];
    const float* Wv = (const float*)d_in[7];
    const float* bv = (const float*)d_in[8];
    const float* Wo = (const float*)d_in[9];
    const float* bo = (const float*)d_in[10];
    float* out = (float*)d_out;

    // ws layout (bytes), total 64,520,192:
    char* p = (char*)d_ws;
    __bf16* Tb  = (__bf16*)(p);              // target bf16   16,777,216  [ab alias]
    __bf16* Sb  = (__bf16*)(p + 16777216);   // source bf16    8,192,000
    __bf16* kb  = (__bf16*)(p + 24969216);   // K proj bf16    2,048,000
    __bf16* vb  = (__bf16*)(p + 27017216);   // V proj bf16    2,048,000
    __bf16* WqT = (__bf16*)(p + 29065216);   // Wq^T bf16      2,097,152
    __bf16* WoT = (__bf16*)(p + 31162368);   // Wo^T bf16      8,388,608
    char*   R   =           p + 39550976;    // region 24,969,216
    __bf16* Vb  = (__bf16*)(R);              // value bf16     8,192,000
    __bf16* WvT = (__bf16*)(R + 8192000);    // Wv^T bf16      8,388,608
    __bf16* WkT = (__bf16*)(R + 16580608);   // Wk^T bf16      8,388,608
    __bf16* qb  = (__bf16*)(R);              // Q proj bf16 (aliases Vb/WvT/WkT-head,
                                             //  written after K/V-proj consumed them)
    __bf16* ab  = (__bf16*)(p);              // attn out bf16 (aliases Tb, dead by then)

    const dim3 blk(256);

    // 1. casts
    cast_f2b_kernel<<<8192, blk, 0, stream>>>(target, Tb, 2097152);
    cast_f2b_kernel<<<4000, blk, 0, stream>>>(source, Sb, 1024000);
    cast_f2b_kernel<<<4000, blk, 0, stream>>>(value,  Vb, 1024000);
    // 2. weight transposes (grid = (N/64, K/64))
    transpose_cast_kernel<<<dim3(16, 16), blk, 0, stream>>>(Wq, WqT, DM, DM);
    transpose_cast_kernel<<<dim3(16, 64), blk, 0, stream>>>(Wk, WkT, DL, DM);
    transpose_cast_kernel<<<dim3(16, 64), blk, 0, stream>>>(Wv, WvT, DL, DM);
    transpose_cast_kernel<<<dim3(64, 16), blk, 0, stream>>>(Wo, WoT, DM, DL);
    // 3. projections (K first, then V, then Q — qb overwrites Vb/WvT/WkT-head)
    gemm_bt_kernel<true><<<dim3(8, 8),  blk, 0, stream>>>(Sb, WkT, bk, kb, S_SZ, DM, DL);
    gemm_bt_kernel<true><<<dim3(8, 8),  blk, 0, stream>>>(Vb, WvT, bv, vb, S_SZ, DM, DL);
    gemm_bt_kernel<true><<<dim3(8, 64), blk, 0, stream>>>(Tb, WqT, bq, qb, B_SZ * L_SZ, DM, DM);
    // 4. attention (writes ab over Tb)
    attn_kernel<<<dim3(16, 128), blk, 0, stream>>>(qb, kb, vb, ab);
    // 5. output projection (fp32 out)
    gemm_bt_kernel<false><<<dim3(32, 64), blk, 0, stream>>>(ab, WoT, bo, out, B_SZ * L_SZ, DL, DM);
}

// Round 3
// 662.325 us; speedup vs baseline: 6.1408x; 2.6522x over previous
//
#include <hip/hip_runtime.h>
#include <hip/hip_bf16.h>
#include <math.h>

#define B_SZ 8
#define L_SZ 1024
#define S_SZ 1000
#define DM   1024      // d_model = H*E = q/k/v row stride
#define DL   4096      // d_llm
#define NH   16
#define EH   64

typedef __bf16 bf16x8 __attribute__((ext_vector_type(8)));
typedef __bf16 bf16x4 __attribute__((ext_vector_type(4)));
typedef float  f32x4  __attribute__((ext_vector_type(4)));

// async 16-byte global -> LDS (DMA, no VGPR round trip)
__device__ __forceinline__ void async16(const void* g, void* l) {
    __builtin_amdgcn_global_load_lds(
        (const __attribute__((address_space(1))) void*)g,
        (__attribute__((address_space(3))) void*)l, 16, 0, 0);
}

// ---------------------------------------------------------------------------
// cast fp32 -> bf16, 4 elems/thread
// ---------------------------------------------------------------------------
__global__ __launch_bounds__(256) void cast_f2b_kernel(
    const float* __restrict__ in, __bf16* __restrict__ out, int n4)
{
    int i = blockIdx.x * 256 + threadIdx.x;
    if (i < n4) {
        float4 x = ((const float4*)in)[i];
        bf16x4 y;
        y.x = (__bf16)x.x; y.y = (__bf16)x.y;
        y.z = (__bf16)x.z; y.w = (__bf16)x.w;
        ((bf16x4*)out)[i] = y;
    }
}

// ---------------------------------------------------------------------------
// W (K,N) fp32 -> WT (N,K) bf16. 64x64 tile. K,N multiples of 64.
// ---------------------------------------------------------------------------
__global__ __launch_bounds__(256) void transpose_cast_kernel(
    const float* __restrict__ W, __bf16* __restrict__ WT, int K, int N)
{
    __shared__ float t[64][68];
    const int k0 = blockIdx.y * 64, n0 = blockIdx.x * 64;
    const int tx = threadIdx.x & 15, ty = threadIdx.x >> 4;

#pragma unroll
    for (int tt = 0; tt < 4; ++tt) {
        int r = ty + 16 * tt;
        float4 x = *(const float4*)&W[(size_t)(k0 + r) * N + n0 + 4 * tx];
        *(float4*)&t[r][4 * tx] = x;
    }
    __syncthreads();
#pragma unroll
    for (int tt = 0; tt < 4; ++tt) {
        int n = ty + 16 * tt;
        bf16x4 y;
        y.x = (__bf16)t[4 * tx + 0][n];
        y.y = (__bf16)t[4 * tx + 1][n];
        y.z = (__bf16)t[4 * tx + 2][n];
        y.w = (__bf16)t[4 * tx + 3][n];
        *(bf16x4*)&WT[(size_t)(n0 + n) * K + k0 + 4 * tx] = y;
    }
}

// ---------------------------------------------------------------------------
// V (S x DM) bf16 -> VT (DM x 1024) bf16, zero-padded for s in [S, 1024).
// ---------------------------------------------------------------------------
__global__ __launch_bounds__(256) void transpose_v_kernel(
    const __bf16* __restrict__ vb, __bf16* __restrict__ vtb)
{
    __shared__ __bf16 t[64][72];
    const int d0 = blockIdx.x * 64, s0 = blockIdx.y * 64;
    const int tid = threadIdx.x;
#pragma unroll
    for (int tt = 0; tt < 2; ++tt) {
        int idx = tt * 256 + tid;          // 0..511
        int r = idx >> 3, ch = idx & 7;    // r = s-row, ch = 16B chunk over d
        bf16x8 val;
        if (s0 + r < S_SZ) {
            val = *(const bf16x8*)&vb[(size_t)(s0 + r) * DM + d0 + ch * 8];
        } else {
#pragma unroll
            for (int j = 0; j < 8; ++j) val[j] = (__bf16)0.f;
        }
        *(bf16x8*)&t[r][ch * 8] = val;
    }
    __syncthreads();
#pragma unroll
    for (int tt = 0; tt < 2; ++tt) {
        int idx = tt * 256 + tid;
        int r = idx >> 3, ch = idx & 7;    // r = d-row in tile, ch over s
        bf16x8 o;
#pragma unroll
        for (int j = 0; j < 8; ++j) o[j] = t[ch * 8 + j][r];
        *(bf16x8*)&vtb[(size_t)(d0 + r) * 1024 + s0 + ch * 8] = o;
    }
}

// ---------------------------------------------------------------------------
// m97-style bf16 MFMA GEMM: C[M,N] = A[M,K] @ BT[N,K]^T + bias
// 128x128 tile, BK=32, 256 thr = 4 waves (2x2), 4x4 MFMA tiles/wave.
// ---------------------------------------------------------------------------
template <bool OUT_BF16>
__global__ __launch_bounds__(256) void gemm_bt_kernel(
    const __bf16* __restrict__ A, const __bf16* __restrict__ BT,
    const float* __restrict__ bias, void* __restrict__ Cv,
    int M, int N, int K)
{
    __shared__ __bf16 As[128 * 32];
    __shared__ __bf16 Bs[128 * 32];

    const int tid  = threadIdx.x;
    const int lane = tid & 63;
    const int wave = tid >> 6;
    const int wr   = wave >> 1;
    const int wc   = wave & 1;
    const int m0   = blockIdx.y * 128;
    const int n0   = blockIdx.x * 128;
    const int lm   = lane & 15;
    const int lq   = lane >> 4;

    f32x4 acc[4][4];
#pragma unroll
    for (int i = 0; i < 4; ++i)
#pragma unroll
        for (int j = 0; j < 4; ++j)
            acc[i][j] = (f32x4){0.f, 0.f, 0.f, 0.f};

    for (int k0 = 0; k0 < K; k0 += 32) {
#pragma unroll
        for (int t = 0; t < 2; ++t) {
            int chunk = t * 256 + tid;
            int r     = chunk >> 2;
            int koff  = (chunk & 3) * 8;
            int gm = m0 + r; if (gm >= M) gm = M - 1;
            async16(A  + (size_t)gm * K + k0 + koff, (char*)As + chunk * 16);
            int gn = n0 + r;
            async16(BT + (size_t)gn * K + k0 + koff, (char*)Bs + chunk * 16);
        }
        __syncthreads();

        bf16x8 af[4], bf_[4];
#pragma unroll
        for (int i = 0; i < 4; ++i) {
            af[i]  = *(const bf16x8*)&As[(wr * 64 + i * 16 + lm) * 32 + lq * 8];
            bf_[i] = *(const bf16x8*)&Bs[(wc * 64 + i * 16 + lm) * 32 + lq * 8];
        }
#pragma unroll
        for (int i = 0; i < 4; ++i)
#pragma unroll
            for (int j = 0; j < 4; ++j)
                acc[i][j] = __builtin_amdgcn_mfma_f32_16x16x32_bf16(
                    af[i], bf_[j], acc[i][j], 0, 0, 0);
        __syncthreads();
    }

#pragma unroll
    for (int i = 0; i < 4; ++i) {
        int gm0 = m0 + wr * 64 + i * 16 + lq * 4;
#pragma unroll
        for (int j = 0; j < 4; ++j) {
            int gn = n0 + wc * 64 + j * 16 + lm;
            float bv = bias[gn];
#pragma unroll
            for (int r = 0; r < 4; ++r) {
                int gm = gm0 + r;
                if (gm < M) {
                    float val = acc[i][j][r] + bv;
                    if (OUT_BF16)
                        ((__bf16*)Cv)[(size_t)gm * N + gn] = (__bf16)val;
                    else
                        ((float*)Cv)[(size_t)gm * N + gn] = val;
                }
            }
        }
    }
}

// ---------------------------------------------------------------------------
// MFMA flash attention. Block = 128 Q rows x one (b,h); 4 waves x 32 rows.
// S chunks of 64. Q frags resident in registers. K/V^T staged via
// global_load_lds with XOR-seg swizzle (conflict-free b128 frag reads).
// P round-trips through wave-private LDS (C-layout -> A-layout).
// LDS: Ks 8K + Vts 8K + Ps 18K = 34.8 KB.
// ---------------------------------------------------------------------------
__global__ __launch_bounds__(256) void attn_mfma_kernel(
    const __bf16* __restrict__ q,   // (B*L, DM)
    const __bf16* __restrict__ k,   // (S, DM)
    const __bf16* __restrict__ vt,  // (DM, 1024) zero-padded s>=S
    __bf16* __restrict__ o)         // (B*L, DM)
{
    __shared__ __bf16 Ks[64 * 64];
    __shared__ __bf16 Vts[64 * 64];
    __shared__ __bf16 Ps[4][32 * 72];

    const int tid  = threadIdx.x;
    const int lane = tid & 63;
    const int wave = tid >> 6;
    const int lm   = lane & 15;
    const int lq   = lane >> 4;
    const int bh = blockIdx.y;
    const int b  = bh >> 4;
    const int h  = bh & 15;
    const int l0 = blockIdx.x * 128;
    const int row0 = b * L_SZ + l0 + wave * 32;

    // Q fragments (A-layout: m=lm, k=lq*8+j), resident in registers
    bf16x8 qf[2][2];
#pragma unroll
    for (int mt = 0; mt < 2; ++mt)
#pragma unroll
        for (int ks = 0; ks < 2; ++ks)
            qf[mt][ks] = *(const bf16x8*)&q[(size_t)(row0 + mt * 16 + lm) * DM
                                           + h * 64 + ks * 32 + lq * 8];

    f32x4 oa[2][4];
    float m_run[2][4], l_run[2][4];
#pragma unroll
    for (int mt = 0; mt < 2; ++mt)
#pragma unroll
        for (int r = 0; r < 4; ++r) {
            m_run[mt][r] = -1e30f;
            l_run[mt][r] = 0.f;
#pragma unroll
            for (int et = 0; et < 4; ++et) oa[mt][et][r] = 0.f;
        }

    for (int s0 = 0; s0 < S_SZ; s0 += 64) {
        __syncthreads();   // prev chunk's Ks/Vts reads done before restage
#pragma unroll
        for (int t = 0; t < 2; ++t) {
            int cc = t * 256 + tid;          // 0..511 16B chunks
            int r = cc >> 3, segL = cc & 7;
            int segG = segL ^ (r & 7);       // source permutation = swizzle
            int sg = s0 + r; if (sg >= S_SZ) sg = S_SZ - 1;
            async16(k  + (size_t)sg * DM + h * 64 + segG * 8,
                    (char*)Ks + cc * 16);
            async16(vt + (size_t)(h * 64 + r) * 1024 + s0 + segG * 8,
                    (char*)Vts + cc * 16);
        }
        __syncthreads();   // drains vmcnt -> staged data visible

        // QK^T
        f32x4 sc[2][4];
#pragma unroll
        for (int mt = 0; mt < 2; ++mt)
#pragma unroll
            for (int nt = 0; nt < 4; ++nt)
                sc[mt][nt] = (f32x4){0.f, 0.f, 0.f, 0.f};
#pragma unroll
        for (int ks = 0; ks < 2; ++ks)
#pragma unroll
            for (int nt = 0; nt < 4; ++nt) {
                bf16x8 bK = *(const bf16x8*)((const char*)Ks
                    + (nt * 16 + lm) * 128 + (((ks * 4 + lq) ^ (lm & 7)) * 16));
#pragma unroll
                for (int mt = 0; mt < 2; ++mt)
                    sc[mt][nt] = __builtin_amdgcn_mfma_f32_16x16x32_bf16(
                        qf[mt][ks], bK, sc[mt][nt], 0, 0, 0);
            }

        // scale + S-tail mask (col = s0 + nt*16 + lm)
#pragma unroll
        for (int nt = 0; nt < 4; ++nt) {
            bool masked = (s0 + nt * 16 + lm >= S_SZ);
#pragma unroll
            for (int mt = 0; mt < 2; ++mt)
#pragma unroll
                for (int r = 0; r < 4; ++r)
                    sc[mt][nt][r] = masked ? -1e30f : sc[mt][nt][r] * 0.125f;
        }

        // online softmax: rows = lq*4+r (C-layout), reduce across 16 lm lanes
        float alpha[2][4];
#pragma unroll
        for (int mt = 0; mt < 2; ++mt)
#pragma unroll
            for (int r = 0; r < 4; ++r) {
                float mx = fmaxf(fmaxf(sc[mt][0][r], sc[mt][1][r]),
                                 fmaxf(sc[mt][2][r], sc[mt][3][r]));
#pragma unroll
                for (int off = 1; off < 16; off <<= 1)
                    mx = fmaxf(mx, __shfl_xor(mx, off));
                float mnew = fmaxf(m_run[mt][r], mx);
                alpha[mt][r] = __expf(m_run[mt][r] - mnew);
                m_run[mt][r] = mnew;
            }

#pragma unroll
        for (int mt = 0; mt < 2; ++mt)
#pragma unroll
            for (int r = 0; r < 4; ++r) {
                float rs = 0.f;
#pragma unroll
                for (int nt = 0; nt < 4; ++nt) {
                    float pv = __expf(sc[mt][nt][r] - m_run[mt][r]);
                    Ps[wave][(mt * 16 + lq * 4 + r) * 72 + nt * 16 + lm] = (__bf16)pv;
                    rs += pv;
                }
#pragma unroll
                for (int off = 1; off < 16; off <<= 1)
                    rs += __shfl_xor(rs, off);
                l_run[mt][r] = l_run[mt][r] * alpha[mt][r] + rs;
#pragma unroll
                for (int et = 0; et < 4; ++et)
                    oa[mt][et][r] *= alpha[mt][r];
            }

        // wave-private P round-trip: drain this wave's LDS writes, no barrier
        asm volatile("s_waitcnt lgkmcnt(0)" ::: "memory");

        // PV: A = P (m=lm, k=s), B = V^T rows e (n=et*16+lm, k=s)
#pragma unroll
        for (int ks = 0; ks < 2; ++ks) {
            bf16x8 aP[2];
#pragma unroll
            for (int mt = 0; mt < 2; ++mt)
                aP[mt] = *(const bf16x8*)&Ps[wave][(mt * 16 + lm) * 72
                                                  + ks * 32 + lq * 8];
#pragma unroll
            for (int et = 0; et < 4; ++et) {
                bf16x8 bV = *(const bf16x8*)((const char*)Vts
                    + (et * 16 + lm) * 128 + (((ks * 4 + lq) ^ (lm & 7)) * 16));
#pragma unroll
                for (int mt = 0; mt < 2; ++mt)
                    oa[mt][et] = __builtin_amdgcn_mfma_f32_16x16x32_bf16(
                        aP[mt], bV, oa[mt][et], 0, 0, 0);
            }
        }
    }

    // epilogue: normalize, store bf16 (C-layout rows lq*4+r, cols et*16+lm)
#pragma unroll
    for (int mt = 0; mt < 2; ++mt)
#pragma unroll
        for (int r = 0; r < 4; ++r) {
            float inv = 1.f / l_run[mt][r];
            size_t rowi = (size_t)(row0 + mt * 16 + lq * 4 + r) * DM + h * 64;
#pragma unroll
            for (int et = 0; et < 4; ++et)
                o[rowi + et * 16 + lm] = (__bf16)(oa[mt][et][r] * inv);
        }
}

// ---------------------------------------------------------------------------
extern "C" void kernel_launch(void* const* d_in, const int* in_sizes, int n_in,
                              void* d_out, int out_size, void* d_ws, size_t ws_size,
                              hipStream_t stream)
{
    const float* target = (const float*)d_in[0];
    const float* source = (const float*)d_in[1];
    const float* value  = (const float*)d_in[2];
    const float* Wq = (const float*)d_in[3];
    const float* bq = (const float*)d_in[4];
    const float* Wk = (const float*)d_in[5];
    const float* bk = (const float*)d_in[6];
    const float* Wv = (const float*)d_in[7];
    const float* bv = (const float*)d_in[8];
    const float* Wo = (const float*)d_in[9];
    const float* bo = (const float*)d_in[10];
    float* out = (float*)d_out;

    // ws layout (bytes), total 64,520,192 (same footprint as round 2):
    char* p = (char*)d_ws;
    __bf16* Tb  = (__bf16*)(p);              // target bf16   16,777,216 [ab alias]
    __bf16* Sb  = (__bf16*)(p + 16777216);   // source bf16    8,192,000
    __bf16* vtb = (__bf16*)(p + 16777216);   // V^T bf16 2,097,152 (aliases Sb,
                                             //  written after K GEMM consumed Sb)
    __bf16* kb  = (__bf16*)(p + 24969216);   // K proj bf16    2,048,000
    __bf16* vb  = (__bf16*)(p + 27017216);   // V proj bf16    2,048,000
    __bf16* WqT = (__bf16*)(p + 29065216);   // Wq^T bf16      2,097,152
    __bf16* WoT = (__bf16*)(p + 31162368);   // Wo^T bf16      8,388,608
    char*   R   =           p + 39550976;    // region 24,969,216
    __bf16* Vb  = (__bf16*)(R);              // value bf16     8,192,000
    __bf16* WvT = (__bf16*)(R + 8192000);    // Wv^T bf16      8,388,608
    __bf16* WkT = (__bf16*)(R + 16580608);   // Wk^T bf16      8,388,608
    __bf16* qb  = (__bf16*)(R);              // Q proj bf16 (aliases Vb/WvT/WkT-
                                             //  head, written after K/V GEMMs)
    __bf16* ab  = (__bf16*)(p);              // attn out (aliases Tb, dead by then)

    const dim3 blk(256);

    // 1. casts
    cast_f2b_kernel<<<8192, blk, 0, stream>>>(target, Tb, 2097152);
    cast_f2b_kernel<<<4000, blk, 0, stream>>>(source, Sb, 1024000);
    cast_f2b_kernel<<<4000, blk, 0, stream>>>(value,  Vb, 1024000);
    // 2. weight transposes
    transpose_cast_kernel<<<dim3(16, 16), blk, 0, stream>>>(Wq, WqT, DM, DM);
    transpose_cast_kernel<<<dim3(16, 64), blk, 0, stream>>>(Wk, WkT, DL, DM);
    transpose_cast_kernel<<<dim3(16, 64), blk, 0, stream>>>(Wv, WvT, DL, DM);
    transpose_cast_kernel<<<dim3(64, 16), blk, 0, stream>>>(Wo, WoT, DM, DL);
    // 3. projections (K first: frees Sb for vtb; then V; then Q over R)
    gemm_bt_kernel<true><<<dim3(8, 8),  blk, 0, stream>>>(Sb, WkT, bk, kb, S_SZ, DM, DL);
    gemm_bt_kernel<true><<<dim3(8, 8),  blk, 0, stream>>>(Vb, WvT, bv, vb, S_SZ, DM, DL);
    transpose_v_kernel<<<dim3(16, 16), blk, 0, stream>>>(vb, vtb);
    gemm_bt_kernel<true><<<dim3(8, 64), blk, 0, stream>>>(Tb, WqT, bq, qb, B_SZ * L_SZ, DM, DM);
    // 4. MFMA flash attention
    attn_mfma_kernel<<<dim3(8, 128), blk, 0, stream>>>(qb, kb, vtb, ab);
    // 5. output projection (fp32 out)
    gemm_bt_kernel<false><<<dim3(32, 64), blk, 0, stream>>>(ab, WoT, bo, out, B_SZ * L_SZ, DL, DM);
}